// Round 19
// baseline (489.797 us; speedup 1.0000x reference)
//
#include <hip/hip_runtime.h>

#define TSEQ 512
#define NTH  512    // 8 waves: 0-3 layer0, 4-7 layer1 (skew 2)
#define BT   8      // 512 blocks -> TARGET 2 blocks/CU (4 waves/SIMD, indep. barriers)
// R19 = R16 kernel + __launch_bounds__(512,4). R12 proved (512,4) DOES co-reside
// (38% occ) but spilled (fat body); R16's lean j-split body didn't spill (68 VGPR)
// but (512,2) never co-resided. This is the untested cell: lean body + forced
// 4 waves/EU. Per-CU: MFMA x2 (543->1086 cyc, new binding pipe), trans/VALU
// unchanged (j-split). Expected wall ~1086-1200 cyc/16-batch vs 1540 now.

typedef __attribute__((ext_vector_type(8))) _Float16 half8;
typedef __attribute__((ext_vector_type(4))) float f32x4;
typedef __attribute__((ext_vector_type(4))) unsigned int u32x4;

__device__ __forceinline__ unsigned pkrtz(float a, float b) {
    return __builtin_bit_cast(unsigned, __builtin_amdgcn_cvt_pkrtz(a, b));
}
__device__ __forceinline__ unsigned packF16x2(float a, float b) {
    _Float16 ha = (_Float16)a, hb = (_Float16)b;
    return (unsigned)__builtin_bit_cast(unsigned short, ha) |
           ((unsigned)__builtin_bit_cast(unsigned short, hb) << 16);
}
__device__ __forceinline__ half8 packA16s(const float w8[8], float s) {
    u32x4 W = { packF16x2(w8[0]*s, w8[1]*s), packF16x2(w8[2]*s, w8[3]*s),
                packF16x2(w8[4]*s, w8[5]*s), packF16x2(w8[6]*s, w8[7]*s) };
    return __builtin_bit_cast(half8, W);
}

#define MFMA(a, b, c) __builtin_amdgcn_mfma_f32_16x16x32_f16((a), (b), (c), 0, 0, 0)
#define LD128H(p) __builtin_bit_cast(half8, *(const u32x4*)(p))
#define EXP2(v) __builtin_amdgcn_exp2f(v)
#define RCP(v)  __builtin_amdgcn_rcpf(v)

// fused LSTM unit update with PRE-SCALED pre-acts (scales folded into W/b):
// ai,af,ao = -log2e * preact;  ag = 2*log2e * preact
__device__ __forceinline__ float act_fused(float ai, float af, float ag, float ao, float* c) {
    const float L2E2 = 2.88539008177792681472f;
    float ei = EXP2(ai);
    float ef = EXP2(af);
    float eg = EXP2(ag);
    float eo = EXP2(ao);
    float sf = RCP(1.0f + ef);
    float ig = (eg - 1.0f) * RCP((1.0f + ei) * (eg + 1.0f));
    float cn = fmaf(*c, sf, ig);
    *c = cn;
    float ec = EXP2(cn * L2E2);
    return (ec - 1.0f) * RCP((1.0f + eo) * (ec + 1.0f));
}

__global__ __launch_bounds__(NTH, 4)
void lstm2_mfma(const float* __restrict__ x,
                const float* __restrict__ W_ih0, const float* __restrict__ W_hh0,
                const float* __restrict__ b_ih0, const float* __restrict__ b_hh0,
                const float* __restrict__ W_ih1, const float* __restrict__ W_hh1,
                const float* __restrict__ b_ih1, const float* __restrict__ b_hh1,
                const float* __restrict__ W_fc,  const float* __restrict__ b_fc,
                float* __restrict__ out)
{
    const int tid  = threadIdx.x;
    const int lane = tid & 63;
    const int wv   = tid >> 6;        // 0-3: layer0, 4-7: layer1
    const int rl   = lane & 15;       // MFMA row/col index
    const int g    = lane >> 4;       // k-group 0..3
    const int n    = rl & 7;          // batch col (cols 8-15 duplicate)
    const int T    = rl >> 3;         // j-half this lane activates (0: j=0,1; 1: j=2,3)
    const int b0   = blockIdx.x * BT;

    const float NL2E  = -1.44269504088896340736f;
    const float PL2E2 =  2.88539008177792681472f;

    // f16 h planes: [8 batch rows x 32 words]; depth-2 ping-pong. h[t] at parity (t+1)&1.
    __shared__ unsigned h0P0[256], h0P1[256];
    __shared__ unsigned h1P0[256], h1P1[256];
    __shared__ float fcl[64 * 9];     // [unit][batch], padded 8->9

    for (int i2 = tid; i2 < 256; i2 += NTH) {
        h0P0[i2] = 0u; h0P1[i2] = 0u; h1P0[i2] = 0u; h1P1[i2] = 0u;
    }
    __syncthreads();

    // diagonal-swizzle offsets (loop-invariant)
    const int offL = n*32 + (((g + n) & 7) << 2);           // b128 read, k-half 0
    const int offH = n*32 + (((4 + g + n) & 7) << 2);       // b128 read, k-half 1
    const int q    = 8*((wv & 3)) + 2*g + T;                // this lane's u32 word (unit-pair)
    const int woff = n*32 + ((((q >> 2) + n) & 7) << 2) + (q & 3);

    if (wv < 4) {
        // ======== LAYER 0: wave w owns units [16w,16w+16) for all 4 gates ========
        const int w = wv;
        half8 A0[4][2];   // [gate][k-half of W_hh0]
        half8 Ax[4];      // x-term: k0-3 = W_ih0 row (g==0 lanes), else 0
        f32x4 bias4[4];
        #pragma unroll
        for (int G = 0; G < 4; ++G) {
            const float sc = (G == 2) ? PL2E2 : NL2E;
            const int row = 64*G + 16*w + rl;
            #pragma unroll
            for (int s = 0; s < 2; ++s) {
                float w8[8];
                const float* src = W_hh0 + row*64 + s*32 + g*8;
                #pragma unroll
                for (int e = 0; e < 8; ++e) w8[e] = src[e];
                A0[G][s] = packA16s(w8, sc);
            }
            {
                u32x4 ax = {0u, 0u, 0u, 0u};
                if (g == 0) {
                    ax.x = packF16x2(W_ih0[row*4+0]*sc, W_ih0[row*4+1]*sc);
                    ax.y = packF16x2(W_ih0[row*4+2]*sc, W_ih0[row*4+3]*sc);
                }
                Ax[G] = __builtin_bit_cast(half8, ax);
            }
            const int rb = 64*G + 16*w + 4*g;
            bias4[G].x = (b_ih0[rb+0] + b_hh0[rb+0]) * sc;
            bias4[G].y = (b_ih0[rb+1] + b_hh0[rb+1]) * sc;
            bias4[G].z = (b_ih0[rb+2] + b_hh0[rb+2]) * sc;
            bias4[G].w = (b_ih0[rb+3] + b_hh0[rb+3]) * sc;
        }
        float cst[2] = {0.f, 0.f};

        // prologue: x[0] load + pre-pack (batch col n; dup lanes broadcast)
        f32x4 xf = *(const f32x4*)(x + ((size_t)(b0 + n) * TSEQ) * 4);
        unsigned bx0 = pkrtz(xf.x, xf.y);
        unsigned bx1 = pkrtz(xf.z, xf.w);

        auto body0 = [&](const unsigned* rP, unsigned* wP, int i) {
            if (i + 1 < TSEQ)
                xf = *(const f32x4*)(x + ((size_t)(b0 + n) * TSEQ + (i + 1)) * 4);

            half8 B0 = LD128H(rP + offL);
            half8 B1 = LD128H(rP + offH);
            u32x4 tx = {0u, 0u, 0u, 0u};
            if (g == 0) { tx.x = bx0; tx.y = bx1; }
            half8 Bx = __builtin_bit_cast(half8, tx);

            f32x4 acc[4];
            __builtin_amdgcn_s_setprio(1);
            #pragma unroll
            for (int G = 0; G < 4; ++G) acc[G] = MFMA(Ax[G], Bx, bias4[G]);
            #pragma unroll
            for (int G = 0; G < 4; ++G) acc[G] = MFMA(A0[G][0], B0, acc[G]);
            #pragma unroll
            for (int G = 0; G < 4; ++G) acc[G] = MFMA(A0[G][1], B1, acc[G]);
            __builtin_amdgcn_s_setprio(0);

            // j-split activation: this lane does its 2 units only
            float s0[4], s1[4];
            #pragma unroll
            for (int G = 0; G < 4; ++G) {
                s0[G] = T ? acc[G].z : acc[G].x;
                s1[G] = T ? acc[G].w : acc[G].y;
            }
            float hv0 = act_fused(s0[0], s0[1], s0[2], s0[3], &cst[0]);
            float hv1 = act_fused(s1[0], s1[1], s1[2], s1[3], &cst[1]);

            bx0 = pkrtz(xf.x, xf.y);
            bx1 = pkrtz(xf.z, xf.w);

            wP[woff] = pkrtz(hv0, hv1);
        };

        for (int ii = 0; ii < 256; ++ii) {
            body0(h0P0, h0P1, 2*ii);     __syncthreads();  // i=2ii   (p=0)
            body0(h0P1, h0P0, 2*ii + 1); __syncthreads();  // i=2ii+1 (p=1)
        }
        __syncthreads();   // i=512 slot (L1 tail)
        __syncthreads();   // i=513 slot (L1 tail)
    } else {
        // ======== LAYER 1 (skew 2): iter i computes t=i-2; h0 frags prefetched at i-1 ====
        const int w = wv - 4;
        half8 A1[4][4];   // s=0,1: W_ih1 (vs h0); s=2,3: W_hh1 (vs h1)
        f32x4 bias4[4];
        #pragma unroll
        for (int G = 0; G < 4; ++G) {
            const float sc = (G == 2) ? PL2E2 : NL2E;
            const int row = 64*G + 16*w + rl;
            #pragma unroll
            for (int s = 0; s < 4; ++s) {
                float w8[8];
                const float* src = (s < 2) ? (W_ih1 + row*64 + s*32 + g*8)
                                           : (W_hh1 + row*64 + (s-2)*32 + g*8);
                #pragma unroll
                for (int e = 0; e < 8; ++e) w8[e] = src[e];
                A1[G][s] = packA16s(w8, sc);
            }
            const int rb = 64*G + 16*w + 4*g;
            bias4[G].x = (b_ih1[rb+0] + b_hh1[rb+0]) * sc;
            bias4[G].y = (b_ih1[rb+1] + b_hh1[rb+1]) * sc;
            bias4[G].z = (b_ih1[rb+2] + b_hh1[rb+2]) * sc;
            bias4[G].w = (b_ih1[rb+3] + b_hh1[rb+3]) * sc;
        }
        float cst[2] = {0.f, 0.f};
        const int u0 = 16*w + 4*g + 2*T;   // first of this lane's 2 units

        half8 pB0 = {}, pB1 = {};   // prefetched h0[t] frags

        auto body1 = [&](const unsigned* r1P, unsigned* wP,
                         const unsigned* n0P, bool wrFC) {
            half8 B2 = LD128H(r1P + offL);
            half8 B3 = LD128H(r1P + offH);

            f32x4 acc[4];
            __builtin_amdgcn_s_setprio(1);
            #pragma unroll
            for (int G = 0; G < 4; ++G) acc[G] = MFMA(A1[G][0], pB0, bias4[G]);
            #pragma unroll
            for (int G = 0; G < 4; ++G) acc[G] = MFMA(A1[G][1], pB1, acc[G]);
            #pragma unroll
            for (int G = 0; G < 4; ++G) acc[G] = MFMA(A1[G][2], B2, acc[G]);
            #pragma unroll
            for (int G = 0; G < 4; ++G) acc[G] = MFMA(A1[G][3], B3, acc[G]);
            __builtin_amdgcn_s_setprio(0);

            // prefetch h0[t+1] now: latency hides under act tail
            pB0 = LD128H(n0P + offL);
            pB1 = LD128H(n0P + offH);

            float s0[4], s1[4];
            #pragma unroll
            for (int G = 0; G < 4; ++G) {
                s0[G] = T ? acc[G].z : acc[G].x;
                s1[G] = T ? acc[G].w : acc[G].y;
            }
            float hv0 = act_fused(s0[0], s0[1], s0[2], s0[3], &cst[0]);
            float hv1 = act_fused(s1[0], s1[1], s1[2], s1[3], &cst[1]);
            wP[woff] = pkrtz(hv0, hv1);
            if (wrFC) {
                fcl[(u0 + 0)*9 + n] = hv0;
                fcl[(u0 + 1)*9 + n] = hv1;
            }
        };

        __syncthreads();                         // i=0 (idle)
        // i=1: prefetch-only — h0[0] lives at parity 1
        pB0 = LD128H(h0P1 + offL);
        pB1 = LD128H(h0P1 + offH);
        __syncthreads();                         // i=1
        for (int ii = 0; ii < 256; ++ii) {
            body1(h1P0, h1P1, h0P0, false);     __syncthreads();  // i=2+2ii (p=0)
            body1(h1P1, h1P0, h0P1, ii == 255); __syncthreads();  // i=3+2ii (p=1)
        }
    }

    // ---- FC: out[b] = h1_last[b,:] . W_fc + b_fc ----
    if (tid < BT) {
        float acc = b_fc[0];
        #pragma unroll 16
        for (int u = 0; u < 64; ++u) acc += fcl[u*9 + tid] * W_fc[u];
        out[b0 + tid] = acc;
    }
}

extern "C" void kernel_launch(void* const* d_in, const int* in_sizes, int n_in,
                              void* d_out, int out_size, void* d_ws, size_t ws_size,
                              hipStream_t stream) {
    const float* x     = (const float*)d_in[0];
    const float* W_ih0 = (const float*)d_in[1];
    const float* W_hh0 = (const float*)d_in[2];
    const float* b_ih0 = (const float*)d_in[3];
    const float* b_hh0 = (const float*)d_in[4];
    const float* W_ih1 = (const float*)d_in[5];
    const float* W_hh1 = (const float*)d_in[6];
    const float* b_ih1 = (const float*)d_in[7];
    const float* b_hh1 = (const float*)d_in[8];
    const float* W_fc  = (const float*)d_in[9];
    const float* b_fc  = (const float*)d_in[10];
    float* out = (float*)d_out;

    dim3 grid(4096 / BT), block(NTH);
    hipLaunchKernelGGL(lstm2_mfma, grid, block, 0, stream,
                       x, W_ih0, W_hh0, b_ih0, b_hh0,
                       W_ih1, W_hh1, b_ih1, b_hh1, W_fc, b_fc, out);
}

// Round 20
// 316.759 us; speedup vs baseline: 1.5463x; 1.5463x over previous
//
#include <hip/hip_runtime.h>

#define TSEQ 512
#define NTH  512    // 8 waves: 0-3 layer0, 4-7 layer1 (skew 2); 16 batch/block, 256 blocks = 1/CU
// R20 (from best=R18): A/B micro-bundle.
// - s_setprio REMOVED: waves are barrier-locksteped; m190 evidence setprio
//   starves the co-wave whose act-phase we need overlapped with our MFMAs.
// - L1 exp scheduling symmetrized (e2/e3 right after their MFMA groups).
// - Dead tail barriers trimmed in L0 (kept only the ones L1 pairs with).

typedef __attribute__((ext_vector_type(8))) _Float16 half8;
typedef __attribute__((ext_vector_type(4))) float f32x4;
typedef __attribute__((ext_vector_type(4))) unsigned int u32x4;

__device__ __forceinline__ unsigned pkrtz(float a, float b) {
    return __builtin_bit_cast(unsigned, __builtin_amdgcn_cvt_pkrtz(a, b));
}
// init-time RNE pack (not hot)
__device__ __forceinline__ unsigned packF16x2(float a, float b) {
    _Float16 ha = (_Float16)a, hb = (_Float16)b;
    return (unsigned)__builtin_bit_cast(unsigned short, ha) |
           ((unsigned)__builtin_bit_cast(unsigned short, hb) << 16);
}
__device__ __forceinline__ half8 packA16s(const float w8[8], float s) {
    u32x4 W = { packF16x2(w8[0]*s, w8[1]*s), packF16x2(w8[2]*s, w8[3]*s),
                packF16x2(w8[4]*s, w8[5]*s), packF16x2(w8[6]*s, w8[7]*s) };
    return __builtin_bit_cast(half8, W);
}

#define MFMA(a, b, c) __builtin_amdgcn_mfma_f32_16x16x32_f16((a), (b), (c), 0, 0, 0)
#define LD128H(p) __builtin_bit_cast(half8, *(const u32x4*)(p))
#define EXP2(v) __builtin_amdgcn_exp2f(v)
#define RCP(v)  __builtin_amdgcn_rcpf(v)

__global__ __launch_bounds__(NTH, 1)
void lstm2_mfma(const float* __restrict__ x,
                const float* __restrict__ W_ih0, const float* __restrict__ W_hh0,
                const float* __restrict__ b_ih0, const float* __restrict__ b_hh0,
                const float* __restrict__ W_ih1, const float* __restrict__ W_hh1,
                const float* __restrict__ b_ih1, const float* __restrict__ b_hh1,
                const float* __restrict__ W_fc,  const float* __restrict__ b_fc,
                float* __restrict__ out)
{
    const int tid  = threadIdx.x;
    const int lane = tid & 63;
    const int wv   = tid >> 6;        // 0-3: layer0, 4-7: layer1
    const int rl   = lane & 15;       // MFMA row/col index = batch col n
    const int g    = lane >> 4;       // k-group 0..3
    const int b0   = blockIdx.x * 16;

    const float NL2E  = -1.44269504088896340736f;  // i,f,o row scale
    const float PL2E2 =  2.88539008177792681472f;  // g row scale
    const float L2E2  =  2.88539008177792681472f;

    // f16 h planes (2 units/word), depth-2 ping-pong, compile-time bases.
    // h[t] lives at parity (t+1)&1.
    __shared__ unsigned h0P0[512], h0P1[512];
    __shared__ unsigned h1P0[512], h1P1[512];
    __shared__ float fcl[64 * 17];    // padded 16->17

    for (int i2 = tid; i2 < 512; i2 += NTH) {
        h0P0[i2] = 0u; h0P1[i2] = 0u; h1P0[i2] = 0u; h1P1[i2] = 0u;
    }
    __syncthreads();

    // diagonal-swizzle b128 read offsets (loop-invariant)
    const int offL = rl*32 + (((g + rl) & 7) << 2);         // k-half 0
    const int offH = rl*32 + (((4 + g + rl) & 7) << 2);     // k-half 1
    const int q0w  = 8*((wv & 3)) + 2*g;
    const int woff = rl*32 + ((((q0w >> 2) + rl) & 7) << 2) + (q0w & 3);

    if (wv < 4) {
        // ======== LAYER 0: wave w owns units [16w,16w+16) for all 4 gates ========
        const int w = wv;
        half8 A0[4][2];   // [gate][k-half of W_hh0]
        half8 Ax[4];      // x-term: k0-3 = W_ih0 row (g==0 lanes), else 0
        f32x4 bias4[4];
        #pragma unroll
        for (int G = 0; G < 4; ++G) {
            const float sc = (G == 2) ? PL2E2 : NL2E;
            const int row = 64*G + 16*w + rl;
            #pragma unroll
            for (int s = 0; s < 2; ++s) {
                float w8[8];
                const float* src = W_hh0 + row*64 + s*32 + g*8;
                #pragma unroll
                for (int e = 0; e < 8; ++e) w8[e] = src[e];
                A0[G][s] = packA16s(w8, sc);
            }
            {
                u32x4 ax = {0u, 0u, 0u, 0u};
                if (g == 0) {
                    ax.x = packF16x2(W_ih0[row*4+0]*sc, W_ih0[row*4+1]*sc);
                    ax.y = packF16x2(W_ih0[row*4+2]*sc, W_ih0[row*4+3]*sc);
                }
                Ax[G] = __builtin_bit_cast(half8, ax);
            }
            const int rb = 64*G + 16*w + 4*g;
            bias4[G].x = (b_ih0[rb+0] + b_hh0[rb+0]) * sc;
            bias4[G].y = (b_ih0[rb+1] + b_hh0[rb+1]) * sc;
            bias4[G].z = (b_ih0[rb+2] + b_hh0[rb+2]) * sc;
            bias4[G].w = (b_ih0[rb+3] + b_hh0[rb+3]) * sc;
        }
        float cst[4] = {0.f, 0.f, 0.f, 0.f};

        // prologue: load x[0] and pre-pack its B-frag words
        f32x4 xf = *(const f32x4*)(x + ((size_t)(b0 + rl) * TSEQ) * 4);
        unsigned bx0 = pkrtz(xf.x, xf.y);
        unsigned bx1 = pkrtz(xf.z, xf.w);

        auto body0 = [&](const unsigned* rP, unsigned* wP, int i) {
            // issue x[t+1] load FIRST (hidden by full body)
            if (i + 1 < TSEQ)
                xf = *(const f32x4*)(x + ((size_t)(b0 + rl) * TSEQ + (i + 1)) * 4);

            half8 B0 = LD128H(rP + offL);
            half8 B1 = LD128H(rP + offH);
            u32x4 tx = {0u, 0u, 0u, 0u};
            if (g == 0) { tx.x = bx0; tx.y = bx1; }
            half8 Bx = __builtin_bit_cast(half8, tx);

            f32x4 a0, a1, a2, a3;
            // gates 0,1 chains first (x-group reg-only leads)
            a0 = MFMA(Ax[0], Bx, bias4[0]);  a1 = MFMA(Ax[1], Bx, bias4[1]);
            a0 = MFMA(A0[0][0], B0, a0);     a1 = MFMA(A0[1][0], B0, a1);
            a0 = MFMA(A0[0][1], B1, a0);     a1 = MFMA(A0[1][1], B1, a1);
            // gates 2,3 chains start; exps of gates 0,1 issue underneath
            a2 = MFMA(Ax[2], Bx, bias4[2]);  a3 = MFMA(Ax[3], Bx, bias4[3]);
            float e0[4], e1[4];
            #pragma unroll
            for (int j = 0; j < 4; ++j) { e0[j] = EXP2(a0[j]); e1[j] = EXP2(a1[j]); }
            a2 = MFMA(A0[2][0], B0, a2);     a3 = MFMA(A0[3][0], B0, a3);
            a2 = MFMA(A0[2][1], B1, a2);     a3 = MFMA(A0[3][1], B1, a3);
            float e2[4], e3[4];
            #pragma unroll
            for (int j = 0; j < 4; ++j) { e2[j] = EXP2(a2[j]); e3[j] = EXP2(a3[j]); }

            // combine tail: cn = c*sig(f) + sig(i)*tanh(g); h = sig(o)*tanh(cn)
            float hv[4];
            #pragma unroll
            for (int j = 0; j < 4; ++j) {
                float sf = RCP(1.0f + e1[j]);
                float ig = (e2[j] - 1.0f) * RCP((1.0f + e0[j]) * (e2[j] + 1.0f));
                float cn = fmaf(cst[j], sf, ig);
                cst[j] = cn;
                float ec = EXP2(cn * L2E2);
                hv[j] = (ec - 1.0f) * RCP((1.0f + e3[j]) * (ec + 1.0f));
            }

            bx0 = pkrtz(xf.x, xf.y);
            bx1 = pkrtz(xf.z, xf.w);

            *(uint2*)(wP + woff) = make_uint2(pkrtz(hv[0], hv[1]), pkrtz(hv[2], hv[3]));
        };

        for (int ii = 0; ii < 256; ++ii) {
            body0(h0P0, h0P1, 2*ii);     __syncthreads();  // i=2ii   (p=0)
            body0(h0P1, h0P0, 2*ii + 1); __syncthreads();  // i=2ii+1 (p=1)
        }
        __syncthreads();   // i=512 slot (L1 tail)
        __syncthreads();   // i=513 slot (L1 tail)
    } else {
        // ======== LAYER 1 (skew 2): iter i computes t=i-2; h0 frags prefetched at i-1 ====
        const int w = wv - 4;
        half8 A1[4][4];   // [gate][s]: s=0,1 W_ih1 k-halves (vs h0); s=2,3 W_hh1 (vs h1)
        f32x4 bias4[4];
        #pragma unroll
        for (int G = 0; G < 4; ++G) {
            const float sc = (G == 2) ? PL2E2 : NL2E;
            const int row = 64*G + 16*w + rl;
            #pragma unroll
            for (int s = 0; s < 4; ++s) {
                float w8[8];
                const float* src = (s < 2) ? (W_ih1 + row*64 + s*32 + g*8)
                                           : (W_hh1 + row*64 + (s-2)*32 + g*8);
                #pragma unroll
                for (int e = 0; e < 8; ++e) w8[e] = src[e];
                A1[G][s] = packA16s(w8, sc);
            }
            const int rb = 64*G + 16*w + 4*g;
            bias4[G].x = (b_ih1[rb+0] + b_hh1[rb+0]) * sc;
            bias4[G].y = (b_ih1[rb+1] + b_hh1[rb+1]) * sc;
            bias4[G].z = (b_ih1[rb+2] + b_hh1[rb+2]) * sc;
            bias4[G].w = (b_ih1[rb+3] + b_hh1[rb+3]) * sc;
        }
        float cst[4] = {0.f, 0.f, 0.f, 0.f};
        const int u0 = 16*w + 4*g;

        half8 pB0 = {}, pB1 = {};   // prefetched h0[t] frags

        auto body1 = [&](const unsigned* r1P, unsigned* wP,
                         const unsigned* n0P, bool wrFC) {
            half8 B2 = LD128H(r1P + offL);
            half8 B3 = LD128H(r1P + offH);

            f32x4 a0, a1, a2, a3;
            // gates 0,1 chains (prefetched h0 operands lead)
            a0 = MFMA(A1[0][0], pB0, bias4[0]);  a1 = MFMA(A1[1][0], pB0, bias4[1]);
            a0 = MFMA(A1[0][1], pB1, a0);        a1 = MFMA(A1[1][1], pB1, a1);
            a0 = MFMA(A1[0][2], B2, a0);         a1 = MFMA(A1[1][2], B2, a1);
            a0 = MFMA(A1[0][3], B3, a0);         a1 = MFMA(A1[1][3], B3, a1);
            // gates 2,3 chains; exps of gates 0,1 underneath
            a2 = MFMA(A1[2][0], pB0, bias4[2]);  a3 = MFMA(A1[3][0], pB0, bias4[3]);
            float e0[4], e1[4];
            #pragma unroll
            for (int j = 0; j < 4; ++j) { e0[j] = EXP2(a0[j]); e1[j] = EXP2(a1[j]); }
            a2 = MFMA(A1[2][1], pB1, a2);        a3 = MFMA(A1[3][1], pB1, a3);
            a2 = MFMA(A1[2][2], B2, a2);         a3 = MFMA(A1[3][2], B2, a3);
            a2 = MFMA(A1[2][3], B3, a2);         a3 = MFMA(A1[3][3], B3, a3);
            float e2[4], e3[4];
            #pragma unroll
            for (int j = 0; j < 4; ++j) { e2[j] = EXP2(a2[j]); e3[j] = EXP2(a3[j]); }

            // prefetch h0[t+1] now: latency hides under combine tail
            pB0 = LD128H(n0P + offL);
            pB1 = LD128H(n0P + offH);

            float hv[4];
            #pragma unroll
            for (int j = 0; j < 4; ++j) {
                float sf = RCP(1.0f + e1[j]);
                float ig = (e2[j] - 1.0f) * RCP((1.0f + e0[j]) * (e2[j] + 1.0f));
                float cn = fmaf(cst[j], sf, ig);
                cst[j] = cn;
                float ec = EXP2(cn * L2E2);
                hv[j] = (ec - 1.0f) * RCP((1.0f + e3[j]) * (ec + 1.0f));
            }
            *(uint2*)(wP + woff) = make_uint2(pkrtz(hv[0], hv[1]), pkrtz(hv[2], hv[3]));
            if (wrFC) {
                #pragma unroll
                for (int j = 0; j < 4; ++j) fcl[(u0 + j)*17 + rl] = hv[j];
            }
        };

        __syncthreads();                         // i=0 (idle)
        // i=1: prefetch-only — h0[0] lives at parity 1
        pB0 = LD128H(h0P1 + offL);
        pB1 = LD128H(h0P1 + offH);
        __syncthreads();                         // i=1
        for (int ii = 0; ii < 256; ++ii) {
            body1(h1P0, h1P1, h0P0, false);     __syncthreads();  // i=2+2ii (p=0)
            body1(h1P1, h1P0, h0P1, ii == 255); __syncthreads();  // i=3+2ii (p=1)
        }
    }

    // ---- FC: out[b] = h1_last[b,:] . W_fc + b_fc ----
    if (tid < 16) {
        float acc = b_fc[0];
        #pragma unroll 16
        for (int u = 0; u < 64; ++u) acc += fcl[u*17 + tid] * W_fc[u];
        out[b0 + tid] = acc;
    }
}

extern "C" void kernel_launch(void* const* d_in, const int* in_sizes, int n_in,
                              void* d_out, int out_size, void* d_ws, size_t ws_size,
                              hipStream_t stream) {
    const float* x     = (const float*)d_in[0];
    const float* W_ih0 = (const float*)d_in[1];
    const float* W_hh0 = (const float*)d_in[2];
    const float* b_ih0 = (const float*)d_in[3];
    const float* b_hh0 = (const float*)d_in[4];
    const float* W_ih1 = (const float*)d_in[5];
    const float* W_hh1 = (const float*)d_in[6];
    const float* b_ih1 = (const float*)d_in[7];
    const float* b_hh1 = (const float*)d_in[8];
    const float* W_fc  = (const float*)d_in[9];
    const float* b_fc  = (const float*)d_in[10];
    float* out = (float*)d_out;

    dim3 grid(4096 / 16), block(NTH);
    hipLaunchKernelGGL(lstm2_mfma, grid, block, 0, stream,
                       x, W_ih0, W_hh0, b_ih0, b_hh0,
                       W_ih1, W_hh1, b_ih1, b_hh1, W_fc, b_fc, out);
}